// Round 13
// baseline (9171.345 us; speedup 1.0000x reference)
//
#include <hip/hip_runtime.h>
#include <math.h>

#define L_ 256
#define B_ 128
#define E_ 512
#define H_ 512
#define G_ 1536   // 3*H

__device__ __forceinline__ float sigm(float x) { return 1.0f / (1.0f + __expf(-x)); }

// ---------------------------------------------------------------------------
// Phase A: gxT[dir][l][col][b] = sum_k emb[xs[l][b]][k] * Wx[k][col] + bias[col]
// (unchanged — validated rounds 1/3/8/9/11/12; ~94% of fp32 vector peak)
// ---------------------------------------------------------------------------
__global__ __launch_bounds__(256) void gx_kernel(
    const int* __restrict__ xs, const float* __restrict__ emb,
    const float* __restrict__ Wf, const float* __restrict__ bf,
    const float* __restrict__ Wb, const float* __restrict__ bbv,
    float* __restrict__ gxT)
{
  __shared__ float As[16 * 128];
  __shared__ float Bs[16 * 132];
  __shared__ int toks[B_];
  const int l = blockIdx.y;
  const int dir = blockIdx.z;
  const int col0 = blockIdx.x * 128;
  const float* __restrict__ Wx = dir ? Wb : Wf;
  const float* __restrict__ bias = dir ? bbv : bf;
  const int t = threadIdx.x;
  if (t < B_) toks[t] = xs[l * B_ + t];
  __syncthreads();
  const int ty = t >> 4, tx = t & 15;
  float acc[8][8];
#pragma unroll
  for (int i = 0; i < 8; i++)
#pragma unroll
    for (int j = 0; j < 8; j++) acc[i][j] = 0.0f;

  for (int k0 = 0; k0 < E_; k0 += 16) {
    {
      const int kk = t >> 4;
      const int cl = (t & 15) * 8;
      const float* src = Wx + (size_t)(k0 + kk) * G_ + col0 + cl;
      float4 v0 = *(const float4*)(src);
      float4 v1 = *(const float4*)(src + 4);
      *(float4*)(&As[kk * 128 + cl]) = v0;
      *(float4*)(&As[kk * 128 + cl + 4]) = v1;
    }
    {
      const int u = t & 15;
      const int v = t >> 4;
#pragma unroll
      for (int i = 0; i < 8; i++) {
        const int b = v * 8 + i;
        Bs[u * 132 + b] = emb[toks[b] * E_ + k0 + u];
      }
    }
    __syncthreads();
#pragma unroll
    for (int kk = 0; kk < 16; kk++) {
      float a[8], bv[8];
      *(float4*)(a)     = *(const float4*)(&As[kk * 128 + ty * 8]);
      *(float4*)(a + 4) = *(const float4*)(&As[kk * 128 + ty * 8 + 4]);
      *(float4*)(bv)     = *(const float4*)(&Bs[kk * 132 + tx * 8]);
      *(float4*)(bv + 4) = *(const float4*)(&Bs[kk * 132 + tx * 8 + 4]);
#pragma unroll
      for (int i = 0; i < 8; i++)
#pragma unroll
        for (int j = 0; j < 8; j++)
          acc[i][j] = fmaf(a[i], bv[j], acc[i][j]);
    }
    __syncthreads();
  }
  const size_t base = ((size_t)dir * L_ + l) * (size_t)G_ * B_;
#pragma unroll
  for (int i = 0; i < 8; i++) {
    const int col = col0 + ty * 8 + i;
    const float bvv = bias[col];
    float4 w0, w1;
    w0.x = acc[i][0] + bvv; w0.y = acc[i][1] + bvv; w0.z = acc[i][2] + bvv; w0.w = acc[i][3] + bvv;
    w1.x = acc[i][4] + bvv; w1.y = acc[i][5] + bvv; w1.z = acc[i][6] + bvv; w1.w = acc[i][7] + bvv;
    float* dst = gxT + base + (size_t)col * B_ + tx * 8;
    *(float4*)(dst)     = w0;
    *(float4*)(dst + 4) = w1;
  }
}

// ---------------------------------------------------------------------------
// One-time weight pre-transpose: wp[dir][ph][slc][g*4+c][k] (24 KB/slice)
// (unchanged — validated round 9)
// ---------------------------------------------------------------------------
__global__ __launch_bounds__(256) void wprep_kernel(
    const float* __restrict__ Uhf, const float* __restrict__ Uhb,
    const float* __restrict__ tUf, const float* __restrict__ tUb,
    float* __restrict__ wp)
{
  const int slc = blockIdx.x;        // 0..127
  const int ph  = blockIdx.y;        // 0..2
  const int dir = blockIdx.z;        // 0..1
  const int J0  = slc * 4;
  const int t   = threadIdx.x;
  const float* U = (ph == 0) ? (dir ? Uhb : Uhf)
                             : ((dir ? tUb : tUf) + (size_t)(ph - 1) * H_ * G_);
  float* dst = wp + (size_t)((dir * 3 + ph) * 128 + slc) * 6144;
  for (int i = t; i < 1536; i += 256) {
    const int g = i >> 9;            // 0..2
    const int k = i & 511;
    const float4 v = *(const float4*)&U[(size_t)k * G_ + g * 512 + J0];
    dst[(g * 4 + 0) * 512 + k] = v.x;
    dst[(g * 4 + 1) * 512 + k] = v.y;
    dst[(g * 4 + 2) * 512 + k] = v.z;
    dst[(g * 4 + 3) * 512 + k] = v.w;
  }
}

// ---------------------------------------------------------------------------
// Recurrence v13: 512 thr / 8 waves; tile = 6 cols x 8 batch over k-range 32
// (lane = kh*32 + cg*16 + bg). W LDS-read issue halved vs v12 (48 b128/thr).
// WL rows padded to 520 (kills cg 4-way bank alias; kh 2-way is free).
// Wave kh-halves merge via SW: kh=0 writes its wave set, barrier, kh=1 +=.
// 8 SW sets -> 76 KB dynamic LDS. Final 8-set reduce; combine on waves 0-3.
// 768 launches; 256 WGs; wg -> (dir = wg&1, slc = wg>>1).
// Buffers: ph0: hs->h1, ph1: h1->h2, ph2: h2->hs.
// ---------------------------------------------------------------------------

#define WLP 520
#define SWP 132

#define LOADC(BUF, C)                                                          \
  do {                                                                         \
    _Pragma("unroll") for (int r = 0; r < 4; ++r)                              \
      _Pragma("unroll") for (int q = 0; q < 2; ++q)                            \
        BUF[r * 2 + q] = s4k[((C) * 4 + r) * 32 + q];                          \
  } while (0)

#define COMPUTE(BUF, C)                                                        \
  do {                                                                         \
    const int ko = kbase + (C) * 4;                                            \
    _Pragma("unroll") for (int g = 0; g < 3; ++g)                              \
      _Pragma("unroll") for (int cc = 0; cc < 2; ++cc) {                       \
        const float4 wv =                                                      \
            *(const float4*)&WL[(size_t)(g * 4 + cgx + cc) * WLP + ko];        \
        _Pragma("unroll") for (int q = 0; q < 2; ++q) {                        \
          const float4 h0 = BUF[0 * 2 + q];                                    \
          const float4 h1 = BUF[1 * 2 + q];                                    \
          const float4 h2 = BUF[2 * 2 + q];                                    \
          const float4 h3 = BUF[3 * 2 + q];                                    \
          float* a = &acc[((g * 2 + cc) * 2 + q) * 4];                         \
          a[0] = fmaf(h0.x, wv.x, fmaf(h1.x, wv.y,                             \
                  fmaf(h2.x, wv.z, fmaf(h3.x, wv.w, a[0]))));                  \
          a[1] = fmaf(h0.y, wv.x, fmaf(h1.y, wv.y,                             \
                  fmaf(h2.y, wv.z, fmaf(h3.y, wv.w, a[1]))));                  \
          a[2] = fmaf(h0.z, wv.x, fmaf(h1.z, wv.y,                             \
                  fmaf(h2.z, wv.z, fmaf(h3.z, wv.w, a[2]))));                  \
          a[3] = fmaf(h0.w, wv.x, fmaf(h1.w, wv.y,                             \
                  fmaf(h2.w, wv.z, fmaf(h3.w, wv.w, a[3]))));                  \
        }                                                                      \
      }                                                                        \
  } while (0)

template <bool USE_WP>
__global__ __launch_bounds__(512) void rec_phase(
    const float* __restrict__ gxT, const float* __restrict__ maskp,
    const float* __restrict__ Uhf, const float* __restrict__ Uhb,
    const float* __restrict__ tUf, const float* __restrict__ tUb,
    const float* __restrict__ tbf, const float* __restrict__ tbb,
    const float* hin, float* hout, const float* hsp,
    const float* __restrict__ wp,
    float* __restrict__ outp, int step, int ph)
{
  extern __shared__ float sm[];
  float* WL   = sm;                       // [12][520]
  float* SW   = sm + 12 * WLP;            // [8 sets][12][132]
  float* OUTS = SW + 8 * 12 * SWP;        // [4][128]

  const int wg   = blockIdx.x;
  const int dir  = wg & 1;
  const int slc  = wg >> 1;       // 0..127
  const int J0   = slc * 4;
  const int t    = threadIdx.x;
  const int lane = t & 63;
  const int w    = t >> 6;        // 0..7
  const int kh   = lane >> 5;         // k sub-half
  const int cg   = (lane >> 4) & 1;   // which 2-of-4 h-cols
  const int cgx  = cg * 2;
  const int bg   = lane & 15;         // batch octet index
  const int kbase = w * 64 + kh * 32;
  const int b0   = lane * 2;          // combine-path batch pair
  const int c2   = w & 3;             // combine col (valid for w<4)
  const int j    = J0 + c2;
  const int l    = dir ? (L_ - 1 - step) : step;

  const float* hinf = hin + (size_t)dir * 65536;           // [512][128]
  float2*       hout2 = ((float2*)hout)     + (size_t)dir * 32768;
  const float2* hin2 = ((const float2*)hin) + (size_t)dir * 32768;
  const float2* hs2  = ((const float2*)hsp) + (size_t)dir * 32768;
  const float4* s4k = ((const float4*)hinf) + (size_t)kbase * 32 + bg * 2;

  // ---- h prologue + gate-input loads first (latency hides under staging)
  float4 A0[8], A1[8];
  LOADC(A0, 0);
  LOADC(A1, 1);

  float2 xz, xr, xn, mv, hc, hp;
  xz.x = xz.y = xr.x = xr.y = xn.x = xn.y = 0.f;
  mv.x = mv.y = 0.f; hc.x = hc.y = 0.f; hp.x = hp.y = 0.f;
  if (ph == 0) {
    const size_t gb = (((size_t)dir * L_ + l) * G_) * B_;
    xz = *(const float2*)&gxT[gb + (size_t)j * B_ + b0];
    xr = *(const float2*)&gxT[gb + (size_t)(512 + j) * B_ + b0];
    xn = *(const float2*)&gxT[gb + (size_t)(1024 + j) * B_ + b0];
    hp = hin2[(size_t)j * 64 + lane];
  } else if (ph == 1) {
    hc = hin2[(size_t)j * 64 + lane];
  } else {
    hc = hin2[(size_t)j * 64 + lane];
    hp = hs2[(size_t)j * 64 + lane];
    mv = *(const float2*)&maskp[l * B_ + b0];
  }

  // ---- stage this phase's weight slice into padded LDS rows
  if constexpr (USE_WP) {
    const float4* slice4 =
        (const float4*)(wp + (size_t)((dir * 3 + ph) * 128 + slc) * 6144);
    for (int i = t; i < 1536; i += 512) {
      const int row = i >> 7;            // /128 float4s per row
      const int k4 = (i & 127) * 4;
      *(float4*)&WL[(size_t)row * WLP + k4] = slice4[i];
    }
  } else {
    const float* U = (ph == 0) ? (dir ? Uhb : Uhf)
                               : ((dir ? tUb : tUf) + (size_t)(ph - 1) * H_ * G_);
    for (int i = t; i < 1536; i += 512) {
      const int g = i >> 9;
      const int k = i & 511;
      const float4 v = *(const float4*)&U[(size_t)k * G_ + g * 512 + J0];
      WL[(g * 4 + 0) * WLP + k] = v.x;
      WL[(g * 4 + 1) * WLP + k] = v.y;
      WL[(g * 4 + 2) * WLP + k] = v.z;
      WL[(g * 4 + 3) * WLP + k] = v.w;
    }
  }
  __syncthreads();

  float acc[48];
#pragma unroll
  for (int i = 0; i < 48; ++i) acc[i] = 0.f;

  // 8 chunks of 4 k-rows, 1-deep register double-buffer
  COMPUTE(A0, 0); LOADC(A0, 2);
  COMPUTE(A1, 1); LOADC(A1, 3);
  COMPUTE(A0, 2); LOADC(A0, 4);
  COMPUTE(A1, 3); LOADC(A1, 5);
  COMPUTE(A0, 4); LOADC(A0, 6);
  COMPUTE(A1, 5); LOADC(A1, 7);
  COMPUTE(A0, 6);
  COMPUTE(A1, 7);

  // ---- kh-half merge + per-wave partials: kh=0 writes, kh=1 adds
  if (kh == 0) {
#pragma unroll
    for (int g = 0; g < 3; ++g)
#pragma unroll
      for (int cc = 0; cc < 2; ++cc)
#pragma unroll
        for (int q = 0; q < 2; ++q) {
          const float* a = &acc[((g * 2 + cc) * 2 + q) * 4];
          float4 p; p.x = a[0]; p.y = a[1]; p.z = a[2]; p.w = a[3];
          *(float4*)&SW[(size_t)(w * 12 + g * 4 + cgx + cc) * SWP + bg * 8 + q * 4] = p;
        }
  }
  __syncthreads();
  if (kh == 1) {
#pragma unroll
    for (int g = 0; g < 3; ++g)
#pragma unroll
      for (int cc = 0; cc < 2; ++cc)
#pragma unroll
        for (int q = 0; q < 2; ++q) {
          const float* a = &acc[((g * 2 + cc) * 2 + q) * 4];
          float* dst = &SW[(size_t)(w * 12 + g * 4 + cgx + cc) * SWP + bg * 8 + q * 4];
          float4 p = *(const float4*)dst;
          p.x += a[0]; p.y += a[1]; p.z += a[2]; p.w += a[3];
          *(float4*)dst = p;
        }
  }
  __syncthreads();

  // cross-wave k-reduce for this thread's (j, b0..b0+1) over 8 sets
  float az0 = 0.f, az1 = 0.f, ar0 = 0.f, ar1 = 0.f, an0 = 0.f, an1 = 0.f;
#pragma unroll
  for (int w8 = 0; w8 < 8; ++w8) {
    const float2 pz = *(const float2*)&SW[(size_t)(w8 * 12 + 0 + c2) * SWP + b0];
    const float2 pr = *(const float2*)&SW[(size_t)(w8 * 12 + 4 + c2) * SWP + b0];
    const float2 pn = *(const float2*)&SW[(size_t)(w8 * 12 + 8 + c2) * SWP + b0];
    az0 += pz.x; az1 += pz.y; ar0 += pr.x; ar1 += pr.y; an0 += pn.x; an1 += pn.y;
  }

  if (ph == 0) {
    float2 st;
    {
      const float z = sigm(xz.x + az0);
      const float r = sigm(xr.x + ar0);
      const float n = tanhf(xn.x + r * an0);
      st.x = (1.0f - z) * hp.x + z * n;
    }
    {
      const float z = sigm(xz.y + az1);
      const float r = sigm(xr.y + ar1);
      const float n = tanhf(xn.y + r * an1);
      st.y = (1.0f - z) * hp.y + z * n;
    }
    if (w < 4) hout2[(size_t)j * 64 + lane] = st;
  } else if (ph == 1) {
    const float* tb = dir ? tbb : tbf;
    const float bz = tb[j], br = tb[512 + j], bn = tb[1024 + j];
    float2 st;
    {
      const float z = sigm(az0 + bz);
      const float r = sigm(ar0 + br);
      const float n = tanhf(r * (an0 + bn));
      st.x = (1.0f - z) * hc.x + z * n;
    }
    {
      const float z = sigm(az1 + bz);
      const float r = sigm(ar1 + br);
      const float n = tanhf(r * (an1 + bn));
      st.y = (1.0f - z) * hc.y + z * n;
    }
    if (w < 4) hout2[(size_t)j * 64 + lane] = st;
  } else {
    const float* tb = dir ? tbb : tbf;
    const float bz = tb[G_ + j], br = tb[G_ + 512 + j], bn = tb[G_ + 1024 + j];
    float hin0, hin1;
    {
      const float z = sigm(az0 + bz);
      const float r = sigm(ar0 + br);
      const float n = tanhf(r * (an0 + bn));
      hin0 = (1.0f - z) * hc.x + z * n;
    }
    {
      const float z = sigm(az1 + bz);
      const float r = sigm(ar1 + br);
      const float n = tanhf(r * (an1 + bn));
      hin1 = (1.0f - z) * hc.y + z * n;
    }
    const float hn0 = mv.x * hin0 + (1.0f - mv.x) * hp.x;
    const float hn1 = mv.y * hin1 + (1.0f - mv.y) * hp.y;
    if (w < 4) {
      float2 st; st.x = hn0; st.y = hn1;
      hout2[(size_t)j * 64 + lane] = st;             // hout == hstate
      OUTS[c2 * 128 + b0]     = hn0 * mv.x;
      OUTS[c2 * 128 + b0 + 1] = hn1 * mv.y;
    }
    __syncthreads();
    if (t < B_) {
      float4 o;
      o.x = OUTS[0 * 128 + t];
      o.y = OUTS[1 * 128 + t];
      o.z = OUTS[2 * 128 + t];
      o.w = OUTS[3 * 128 + t];
      *(float4*)(&outp[((size_t)l * B_ + t) * 1024 + dir * 512 + J0]) = o;
    }
  }
}

// ---------------------------------------------------------------------------
extern "C" void kernel_launch(void* const* d_in, const int* in_sizes, int n_in,
                              void* d_out, int out_size, void* d_ws, size_t ws_size,
                              hipStream_t stream) {
  const int*   xs   = (const int*)d_in[0];
  const float* mask = (const float*)d_in[1];
  const float* emb  = (const float*)d_in[2];
  const float* fWx  = (const float*)d_in[3];
  const float* fUh  = (const float*)d_in[4];
  const float* fb   = (const float*)d_in[5];
  const float* bWx  = (const float*)d_in[6];
  const float* bUh  = (const float*)d_in[7];
  const float* bb   = (const float*)d_in[8];
  const float* ftU  = (const float*)d_in[9];
  const float* ftb  = (const float*)d_in[10];
  const float* btU  = (const float*)d_in[11];
  const float* btb  = (const float*)d_in[12];
  float* out = (float*)d_out;

  // ws: gxT[2][256][1536][128] | hstate | htmp1 | htmp2 | (optional) wp
  float* gxT    = (float*)d_ws;
  float* hstate = gxT + (size_t)2 * L_ * G_ * B_;
  float* htmp1  = hstate + (size_t)2 * H_ * B_;
  float* htmp2  = htmp1 + (size_t)2 * H_ * B_;
  float* wp_buf = htmp2 + (size_t)2 * H_ * B_;

  const size_t need_wp = ((size_t)2 * L_ * G_ * B_ + (size_t)6 * H_ * B_ +
                          (size_t)2 * 3 * 128 * 6144) * sizeof(float);
  const bool use_wp = (ws_size >= need_wp);
  const float* wpp = use_wp ? wp_buf : nullptr;

  const unsigned lds_bytes =
      (12 * WLP + 8 * 12 * SWP + 4 * 128) * sizeof(float);   // 77696 B

  // zero initial h (replay-safe)
  hipMemsetAsync(hstate, 0, (size_t)2 * H_ * B_ * sizeof(float), stream);

  if (use_wp) {
    dim3 gW(128, 3, 2);
    wprep_kernel<<<gW, 256, 0, stream>>>(fUh, bUh, ftU, btU, wp_buf);
  }

  dim3 gA(G_ / 128, L_, 2);
  gx_kernel<<<gA, 256, 0, stream>>>(xs, emb, fWx, fb, bWx, bb, gxT);

  if (use_wp) {
    for (int step = 0; step < L_; ++step) {
      rec_phase<true><<<256, 512, lds_bytes, stream>>>(
          gxT, mask, fUh, bUh, ftU, btU, ftb, btb,
          hstate, htmp1, hstate, wpp, out, step, 0);
      rec_phase<true><<<256, 512, lds_bytes, stream>>>(
          gxT, mask, fUh, bUh, ftU, btU, ftb, btb,
          htmp1, htmp2, hstate, wpp, out, step, 1);
      rec_phase<true><<<256, 512, lds_bytes, stream>>>(
          gxT, mask, fUh, bUh, ftU, btU, ftb, btb,
          htmp2, hstate, hstate, wpp, out, step, 2);
    }
  } else {
    for (int step = 0; step < L_; ++step) {
      rec_phase<false><<<256, 512, lds_bytes, stream>>>(
          gxT, mask, fUh, bUh, ftU, btU, ftb, btb,
          hstate, htmp1, hstate, wpp, out, step, 0);
      rec_phase<false><<<256, 512, lds_bytes, stream>>>(
          gxT, mask, fUh, bUh, ftU, btU, ftb, btb,
          htmp1, htmp2, hstate, wpp, out, step, 1);
      rec_phase<false><<<256, 512, lds_bytes, stream>>>(
          gxT, mask, fUh, bUh, ftU, btU, ftb, btb,
          htmp2, hstate, hstate, wpp, out, step, 2);
    }
  }
}

// Round 14
// 8839.718 us; speedup vs baseline: 1.0375x; 1.0375x over previous
//
#include <hip/hip_runtime.h>
#include <math.h>

#define L_ 256
#define B_ 128
#define E_ 512
#define H_ 512
#define G_ 1536   // 3*H

__device__ __forceinline__ float sigm(float x) { return 1.0f / (1.0f + __expf(-x)); }

// ---------------------------------------------------------------------------
// Phase A: gxT[dir][l][col][b] = sum_k emb[xs[l][b]][k] * Wx[k][col] + bias[col]
// (unchanged — validated rounds 1/3/8/9/11/12/13; ~94% of fp32 vector peak)
// ---------------------------------------------------------------------------
__global__ __launch_bounds__(256) void gx_kernel(
    const int* __restrict__ xs, const float* __restrict__ emb,
    const float* __restrict__ Wf, const float* __restrict__ bf,
    const float* __restrict__ Wb, const float* __restrict__ bbv,
    float* __restrict__ gxT)
{
  __shared__ float As[16 * 128];
  __shared__ float Bs[16 * 132];
  __shared__ int toks[B_];
  const int l = blockIdx.y;
  const int dir = blockIdx.z;
  const int col0 = blockIdx.x * 128;
  const float* __restrict__ Wx = dir ? Wb : Wf;
  const float* __restrict__ bias = dir ? bbv : bf;
  const int t = threadIdx.x;
  if (t < B_) toks[t] = xs[l * B_ + t];
  __syncthreads();
  const int ty = t >> 4, tx = t & 15;
  float acc[8][8];
#pragma unroll
  for (int i = 0; i < 8; i++)
#pragma unroll
    for (int j = 0; j < 8; j++) acc[i][j] = 0.0f;

  for (int k0 = 0; k0 < E_; k0 += 16) {
    {
      const int kk = t >> 4;
      const int cl = (t & 15) * 8;
      const float* src = Wx + (size_t)(k0 + kk) * G_ + col0 + cl;
      float4 v0 = *(const float4*)(src);
      float4 v1 = *(const float4*)(src + 4);
      *(float4*)(&As[kk * 128 + cl]) = v0;
      *(float4*)(&As[kk * 128 + cl + 4]) = v1;
    }
    {
      const int u = t & 15;
      const int v = t >> 4;
#pragma unroll
      for (int i = 0; i < 8; i++) {
        const int b = v * 8 + i;
        Bs[u * 132 + b] = emb[toks[b] * E_ + k0 + u];
      }
    }
    __syncthreads();
#pragma unroll
    for (int kk = 0; kk < 16; kk++) {
      float a[8], bv[8];
      *(float4*)(a)     = *(const float4*)(&As[kk * 128 + ty * 8]);
      *(float4*)(a + 4) = *(const float4*)(&As[kk * 128 + ty * 8 + 4]);
      *(float4*)(bv)     = *(const float4*)(&Bs[kk * 132 + tx * 8]);
      *(float4*)(bv + 4) = *(const float4*)(&Bs[kk * 132 + tx * 8 + 4]);
#pragma unroll
      for (int i = 0; i < 8; i++)
#pragma unroll
        for (int j = 0; j < 8; j++)
          acc[i][j] = fmaf(a[i], bv[j], acc[i][j]);
    }
    __syncthreads();
  }
  const size_t base = ((size_t)dir * L_ + l) * (size_t)G_ * B_;
#pragma unroll
  for (int i = 0; i < 8; i++) {
    const int col = col0 + ty * 8 + i;
    const float bvv = bias[col];
    float4 w0, w1;
    w0.x = acc[i][0] + bvv; w0.y = acc[i][1] + bvv; w0.z = acc[i][2] + bvv; w0.w = acc[i][3] + bvv;
    w1.x = acc[i][4] + bvv; w1.y = acc[i][5] + bvv; w1.z = acc[i][6] + bvv; w1.w = acc[i][7] + bvv;
    float* dst = gxT + base + (size_t)col * B_ + tx * 8;
    *(float4*)(dst)     = w0;
    *(float4*)(dst + 4) = w1;
  }
}

// ---------------------------------------------------------------------------
// One-time weight pre-transpose: wp[dir][ph][slc][g*4+c][k] (24 KB/slice)
// (unchanged — validated round 9)
// ---------------------------------------------------------------------------
__global__ __launch_bounds__(256) void wprep_kernel(
    const float* __restrict__ Uhf, const float* __restrict__ Uhb,
    const float* __restrict__ tUf, const float* __restrict__ tUb,
    float* __restrict__ wp)
{
  const int slc = blockIdx.x;        // 0..127
  const int ph  = blockIdx.y;        // 0..2
  const int dir = blockIdx.z;        // 0..1
  const int J0  = slc * 4;
  const int t   = threadIdx.x;
  const float* U = (ph == 0) ? (dir ? Uhb : Uhf)
                             : ((dir ? tUb : tUf) + (size_t)(ph - 1) * H_ * G_);
  float* dst = wp + (size_t)((dir * 3 + ph) * 128 + slc) * 6144;
  for (int i = t; i < 1536; i += 256) {
    const int g = i >> 9;            // 0..2
    const int k = i & 511;
    const float4 v = *(const float4*)&U[(size_t)k * G_ + g * 512 + J0];
    dst[(g * 4 + 0) * 512 + k] = v.x;
    dst[(g * 4 + 1) * 512 + k] = v.y;
    dst[(g * 4 + 2) * 512 + k] = v.z;
    dst[(g * 4 + 3) * 512 + k] = v.w;
  }
}

// ---------------------------------------------------------------------------
// Recurrence v14 = R12 tile (512 thr / 8 waves; wave w owns k in [64w,64w+64);
// thread = 6 gate-cols x 4 batch) with a SINGLE-STAGE cross-wave reduce:
// all 8 waves write their own SW set (8 x 12 x 128, 74 KB dynamic LDS),
// one barrier, then an 8-set reduce. Removes one __syncthreads and the
// waves-4..7 LDS read-modify-write pass from R12's critical path.
// 768 launches; 256 WGs; wg -> (dir = wg&1, slc = wg>>1).
// Buffers: ph0: hs->h1, ph1: h1->h2, ph2: h2->hs.
// ---------------------------------------------------------------------------

#define LOADC(BUF, C)                                                          \
  do {                                                                         \
    _Pragma("unroll") for (int it = 0; it < 16; ++it)                          \
        BUF[it] = s4k[((C) * 16 + it) * 32];                                   \
  } while (0)

#define COMPUTE(BUF, C)                                                        \
  do {                                                                         \
    _Pragma("unroll") for (int k4 = 0; k4 < 4; ++k4) {                         \
      const int ko = kbase + (C) * 16 + k4 * 4;                                \
      const float4 hv0 = BUF[k4 * 4 + 0];                                      \
      const float4 hv1 = BUF[k4 * 4 + 1];                                      \
      const float4 hv2 = BUF[k4 * 4 + 2];                                      \
      const float4 hv3 = BUF[k4 * 4 + 3];                                      \
      _Pragma("unroll") for (int g = 0; g < 3; ++g) {                          \
        _Pragma("unroll") for (int c = 0; c < 2; ++c) {                        \
          const float4 wv =                                                    \
              *(const float4*)&WL[(size_t)(g * 4 + 2 * cg + c) * 512 + ko];    \
          acc[g][c][0] = fmaf(hv0.x, wv.x, fmaf(hv1.x, wv.y,                   \
                          fmaf(hv2.x, wv.z, fmaf(hv3.x, wv.w, acc[g][c][0])))); \
          acc[g][c][1] = fmaf(hv0.y, wv.x, fmaf(hv1.y, wv.y,                   \
                          fmaf(hv2.y, wv.z, fmaf(hv3.y, wv.w, acc[g][c][1])))); \
          acc[g][c][2] = fmaf(hv0.z, wv.x, fmaf(hv1.z, wv.y,                   \
                          fmaf(hv2.z, wv.z, fmaf(hv3.z, wv.w, acc[g][c][2])))); \
          acc[g][c][3] = fmaf(hv0.w, wv.x, fmaf(hv1.w, wv.y,                   \
                          fmaf(hv2.w, wv.z, fmaf(hv3.w, wv.w, acc[g][c][3])))); \
        }                                                                      \
      }                                                                        \
    }                                                                          \
  } while (0)

template <bool USE_WP>
__global__ __launch_bounds__(512) void rec_phase(
    const float* __restrict__ gxT, const float* __restrict__ maskp,
    const float* __restrict__ Uhf, const float* __restrict__ Uhb,
    const float* __restrict__ tUf, const float* __restrict__ tUb,
    const float* __restrict__ tbf, const float* __restrict__ tbb,
    const float* hin, float* hout, const float* hsp,
    const float* __restrict__ wp,
    float* __restrict__ outp, int step, int ph)
{
  extern __shared__ float sm[];
  float* WL   = sm;                      // [12][512]   = 24 KB
  float* SW   = sm + 12 * 512;           // [8][12][128] = 48 KB
  float* OUTS = SW + 8 * 12 * 128;       // [4][128]    = 2 KB

  const int wg   = blockIdx.x;
  const int dir  = wg & 1;
  const int slc  = wg >> 1;       // 0..127
  const int J0   = slc * 4;
  const int t    = threadIdx.x;
  const int lane = t & 63;
  const int w    = t >> 6;        // 0..7
  const int kbase = w * 64;       // 8-way k-split
  const int bq   = lane & 31;     // batch quad index (GEMM tile)
  const int cg   = lane >> 5;     // h-col pair within the 4-col slice
  const int b0   = lane * 2;      // combine-path batch pair
  const int c2   = w & 3;         // combine col (valid for w<4)
  const int j    = J0 + c2;
  const int l    = dir ? (L_ - 1 - step) : step;

  const float* hinf = hin + (size_t)dir * 65536;           // [512][128]
  float2*       hout2 = ((float2*)hout)     + (size_t)dir * 32768;
  const float2* hin2 = ((const float2*)hin) + (size_t)dir * 32768;
  const float2* hs2  = ((const float2*)hsp) + (size_t)dir * 32768;
  const float4* s4k = ((const float4*)hinf) + bq + (size_t)kbase * 32;

  // ---- h prologue + gate-input loads first (latency hides under staging)
  float4 A0[16], A1[16];
  LOADC(A0, 0);
  LOADC(A1, 1);

  float2 xz, xr, xn, mv, hc, hp;
  xz.x = xz.y = xr.x = xr.y = xn.x = xn.y = 0.f;
  mv.x = mv.y = 0.f; hc.x = hc.y = 0.f; hp.x = hp.y = 0.f;
  if (ph == 0) {
    const size_t gb = (((size_t)dir * L_ + l) * G_) * B_;
    xz = *(const float2*)&gxT[gb + (size_t)j * B_ + b0];
    xr = *(const float2*)&gxT[gb + (size_t)(512 + j) * B_ + b0];
    xn = *(const float2*)&gxT[gb + (size_t)(1024 + j) * B_ + b0];
    hp = hin2[(size_t)j * 64 + lane];
  } else if (ph == 1) {
    hc = hin2[(size_t)j * 64 + lane];
  } else {
    hc = hin2[(size_t)j * 64 + lane];
    hp = hs2[(size_t)j * 64 + lane];
    mv = *(const float2*)&maskp[l * B_ + b0];
  }

  // ---- stage this phase's 24 KB weight slice into LDS (512 threads)
  if constexpr (USE_WP) {
    const float* slice = wp + (size_t)((dir * 3 + ph) * 128 + slc) * 6144;
    for (int i = t * 4; i < 6144; i += 2048)
      *(float4*)&WL[i] = *(const float4*)&slice[i];
  } else {
    const float* U = (ph == 0) ? (dir ? Uhb : Uhf)
                               : ((dir ? tUb : tUf) + (size_t)(ph - 1) * H_ * G_);
    for (int i = t; i < 1536; i += 512) {
      const int g = i >> 9;
      const int k = i & 511;
      const float4 v = *(const float4*)&U[(size_t)k * G_ + g * 512 + J0];
      WL[(g * 4 + 0) * 512 + k] = v.x;
      WL[(g * 4 + 1) * 512 + k] = v.y;
      WL[(g * 4 + 2) * 512 + k] = v.z;
      WL[(g * 4 + 3) * 512 + k] = v.w;
    }
  }
  __syncthreads();

  float acc[3][2][4];
#pragma unroll
  for (int g = 0; g < 3; ++g)
#pragma unroll
    for (int c = 0; c < 2; ++c)
#pragma unroll
      for (int b = 0; b < 4; ++b) acc[g][c][b] = 0.f;

  // 4 chunks of 16 k-rows, 1-deep register double-buffer
  COMPUTE(A0, 0); LOADC(A0, 2);
  COMPUTE(A1, 1); LOADC(A1, 3);
  COMPUTE(A0, 2);
  COMPUTE(A1, 3);

  // ---- single-stage: every wave writes its own SW set
#pragma unroll
  for (int g = 0; g < 3; ++g)
#pragma unroll
    for (int c = 0; c < 2; ++c) {
      float4 p;
      p.x = acc[g][c][0]; p.y = acc[g][c][1];
      p.z = acc[g][c][2]; p.w = acc[g][c][3];
      *(float4*)&SW[(size_t)(w * 12 + g * 4 + 2 * cg + c) * 128 + bq * 4] = p;
    }
  __syncthreads();

  // cross-wave k-reduce for this thread's (j, b0..b0+1) over 8 sets
  float az0 = 0.f, az1 = 0.f, ar0 = 0.f, ar1 = 0.f, an0 = 0.f, an1 = 0.f;
#pragma unroll
  for (int w8 = 0; w8 < 8; ++w8) {
    const float2 pz = *(const float2*)&SW[(size_t)(w8 * 12 + 0 + c2) * 128 + b0];
    const float2 pr = *(const float2*)&SW[(size_t)(w8 * 12 + 4 + c2) * 128 + b0];
    const float2 pn = *(const float2*)&SW[(size_t)(w8 * 12 + 8 + c2) * 128 + b0];
    az0 += pz.x; az1 += pz.y; ar0 += pr.x; ar1 += pr.y; an0 += pn.x; an1 += pn.y;
  }

  if (ph == 0) {
    float2 st;
    {
      const float z = sigm(xz.x + az0);
      const float r = sigm(xr.x + ar0);
      const float n = tanhf(xn.x + r * an0);
      st.x = (1.0f - z) * hp.x + z * n;
    }
    {
      const float z = sigm(xz.y + az1);
      const float r = sigm(xr.y + ar1);
      const float n = tanhf(xn.y + r * an1);
      st.y = (1.0f - z) * hp.y + z * n;
    }
    if (w < 4) hout2[(size_t)j * 64 + lane] = st;
  } else if (ph == 1) {
    const float* tb = dir ? tbb : tbf;
    const float bz = tb[j], br = tb[512 + j], bn = tb[1024 + j];
    float2 st;
    {
      const float z = sigm(az0 + bz);
      const float r = sigm(ar0 + br);
      const float n = tanhf(r * (an0 + bn));
      st.x = (1.0f - z) * hc.x + z * n;
    }
    {
      const float z = sigm(az1 + bz);
      const float r = sigm(ar1 + br);
      const float n = tanhf(r * (an1 + bn));
      st.y = (1.0f - z) * hc.y + z * n;
    }
    if (w < 4) hout2[(size_t)j * 64 + lane] = st;
  } else {
    const float* tb = dir ? tbb : tbf;
    const float bz = tb[G_ + j], br = tb[G_ + 512 + j], bn = tb[G_ + 1024 + j];
    float hin0, hin1;
    {
      const float z = sigm(az0 + bz);
      const float r = sigm(ar0 + br);
      const float n = tanhf(r * (an0 + bn));
      hin0 = (1.0f - z) * hc.x + z * n;
    }
    {
      const float z = sigm(az1 + bz);
      const float r = sigm(ar1 + br);
      const float n = tanhf(r * (an1 + bn));
      hin1 = (1.0f - z) * hc.y + z * n;
    }
    const float hn0 = mv.x * hin0 + (1.0f - mv.x) * hp.x;
    const float hn1 = mv.y * hin1 + (1.0f - mv.y) * hp.y;
    if (w < 4) {
      float2 st; st.x = hn0; st.y = hn1;
      hout2[(size_t)j * 64 + lane] = st;             // hout == hstate
      OUTS[c2 * 128 + b0]     = hn0 * mv.x;
      OUTS[c2 * 128 + b0 + 1] = hn1 * mv.y;
    }
    __syncthreads();
    if (t < B_) {
      float4 o;
      o.x = OUTS[0 * 128 + t];
      o.y = OUTS[1 * 128 + t];
      o.z = OUTS[2 * 128 + t];
      o.w = OUTS[3 * 128 + t];
      *(float4*)(&outp[((size_t)l * B_ + t) * 1024 + dir * 512 + J0]) = o;
    }
  }
}

// ---------------------------------------------------------------------------
extern "C" void kernel_launch(void* const* d_in, const int* in_sizes, int n_in,
                              void* d_out, int out_size, void* d_ws, size_t ws_size,
                              hipStream_t stream) {
  const int*   xs   = (const int*)d_in[0];
  const float* mask = (const float*)d_in[1];
  const float* emb  = (const float*)d_in[2];
  const float* fWx  = (const float*)d_in[3];
  const float* fUh  = (const float*)d_in[4];
  const float* fb   = (const float*)d_in[5];
  const float* bWx  = (const float*)d_in[6];
  const float* bUh  = (const float*)d_in[7];
  const float* bb   = (const float*)d_in[8];
  const float* ftU  = (const float*)d_in[9];
  const float* ftb  = (const float*)d_in[10];
  const float* btU  = (const float*)d_in[11];
  const float* btb  = (const float*)d_in[12];
  float* out = (float*)d_out;

  // ws: gxT[2][256][1536][128] | hstate | htmp1 | htmp2 | (optional) wp
  float* gxT    = (float*)d_ws;
  float* hstate = gxT + (size_t)2 * L_ * G_ * B_;
  float* htmp1  = hstate + (size_t)2 * H_ * B_;
  float* htmp2  = htmp1 + (size_t)2 * H_ * B_;
  float* wp_buf = htmp2 + (size_t)2 * H_ * B_;

  const size_t need_wp = ((size_t)2 * L_ * G_ * B_ + (size_t)6 * H_ * B_ +
                          (size_t)2 * 3 * 128 * 6144) * sizeof(float);
  const bool use_wp = (ws_size >= need_wp);
  const float* wpp = use_wp ? wp_buf : nullptr;

  const unsigned lds_bytes =
      (12 * 512 + 8 * 12 * 128 + 4 * 128) * sizeof(float);   // 75776 B

  // zero initial h (replay-safe)
  hipMemsetAsync(hstate, 0, (size_t)2 * H_ * B_ * sizeof(float), stream);

  if (use_wp) {
    dim3 gW(128, 3, 2);
    wprep_kernel<<<gW, 256, 0, stream>>>(fUh, bUh, ftU, btU, wp_buf);
  }

  dim3 gA(G_ / 128, L_, 2);
  gx_kernel<<<gA, 256, 0, stream>>>(xs, emb, fWx, fb, bWx, bb, gxT);

  if (use_wp) {
    for (int step = 0; step < L_; ++step) {
      rec_phase<true><<<256, 512, lds_bytes, stream>>>(
          gxT, mask, fUh, bUh, ftU, btU, ftb, btb,
          hstate, htmp1, hstate, wpp, out, step, 0);
      rec_phase<true><<<256, 512, lds_bytes, stream>>>(
          gxT, mask, fUh, bUh, ftU, btU, ftb, btb,
          htmp1, htmp2, hstate, wpp, out, step, 1);
      rec_phase<true><<<256, 512, lds_bytes, stream>>>(
          gxT, mask, fUh, bUh, ftU, btU, ftb, btb,
          htmp2, hstate, hstate, wpp, out, step, 2);
    }
  } else {
    for (int step = 0; step < L_; ++step) {
      rec_phase<false><<<256, 512, lds_bytes, stream>>>(
          gxT, mask, fUh, bUh, ftU, btU, ftb, btb,
          hstate, htmp1, hstate, wpp, out, step, 0);
      rec_phase<false><<<256, 512, lds_bytes, stream>>>(
          gxT, mask, fUh, bUh, ftU, btU, ftb, btb,
          htmp1, htmp2, hstate, wpp, out, step, 1);
      rec_phase<false><<<256, 512, lds_bytes, stream>>>(
          gxT, mask, fUh, bUh, ftU, btU, ftb, btb,
          htmp2, hstate, hstate, wpp, out, step, 2);
    }
  }
}

// Round 15
// 8744.723 us; speedup vs baseline: 1.0488x; 1.0109x over previous
//
#include <hip/hip_runtime.h>
#include <math.h>

#define L_ 256
#define B_ 128
#define E_ 512
#define H_ 512
#define G_ 1536   // 3*H

__device__ __forceinline__ float sigm(float x) { return 1.0f / (1.0f + __expf(-x)); }

// ---------------------------------------------------------------------------
// Phase A: gxT[dir][l][col][b] = sum_k emb[xs[l][b]][k] * Wx[k][col] + bias[col]
// (unchanged — validated rounds 1/3/8/9/11/12/13/14; ~94% of fp32 vector peak)
// ---------------------------------------------------------------------------
__global__ __launch_bounds__(256) void gx_kernel(
    const int* __restrict__ xs, const float* __restrict__ emb,
    const float* __restrict__ Wf, const float* __restrict__ bf,
    const float* __restrict__ Wb, const float* __restrict__ bbv,
    float* __restrict__ gxT)
{
  __shared__ float As[16 * 128];
  __shared__ float Bs[16 * 132];
  __shared__ int toks[B_];
  const int l = blockIdx.y;
  const int dir = blockIdx.z;
  const int col0 = blockIdx.x * 128;
  const float* __restrict__ Wx = dir ? Wb : Wf;
  const float* __restrict__ bias = dir ? bbv : bf;
  const int t = threadIdx.x;
  if (t < B_) toks[t] = xs[l * B_ + t];
  __syncthreads();
  const int ty = t >> 4, tx = t & 15;
  float acc[8][8];
#pragma unroll
  for (int i = 0; i < 8; i++)
#pragma unroll
    for (int j = 0; j < 8; j++) acc[i][j] = 0.0f;

  for (int k0 = 0; k0 < E_; k0 += 16) {
    {
      const int kk = t >> 4;
      const int cl = (t & 15) * 8;
      const float* src = Wx + (size_t)(k0 + kk) * G_ + col0 + cl;
      float4 v0 = *(const float4*)(src);
      float4 v1 = *(const float4*)(src + 4);
      *(float4*)(&As[kk * 128 + cl]) = v0;
      *(float4*)(&As[kk * 128 + cl + 4]) = v1;
    }
    {
      const int u = t & 15;
      const int v = t >> 4;
#pragma unroll
      for (int i = 0; i < 8; i++) {
        const int b = v * 8 + i;
        Bs[u * 132 + b] = emb[toks[b] * E_ + k0 + u];
      }
    }
    __syncthreads();
#pragma unroll
    for (int kk = 0; kk < 16; kk++) {
      float a[8], bv[8];
      *(float4*)(a)     = *(const float4*)(&As[kk * 128 + ty * 8]);
      *(float4*)(a + 4) = *(const float4*)(&As[kk * 128 + ty * 8 + 4]);
      *(float4*)(bv)     = *(const float4*)(&Bs[kk * 132 + tx * 8]);
      *(float4*)(bv + 4) = *(const float4*)(&Bs[kk * 132 + tx * 8 + 4]);
#pragma unroll
      for (int i = 0; i < 8; i++)
#pragma unroll
        for (int j = 0; j < 8; j++)
          acc[i][j] = fmaf(a[i], bv[j], acc[i][j]);
    }
    __syncthreads();
  }
  const size_t base = ((size_t)dir * L_ + l) * (size_t)G_ * B_;
#pragma unroll
  for (int i = 0; i < 8; i++) {
    const int col = col0 + ty * 8 + i;
    const float bvv = bias[col];
    float4 w0, w1;
    w0.x = acc[i][0] + bvv; w0.y = acc[i][1] + bvv; w0.z = acc[i][2] + bvv; w0.w = acc[i][3] + bvv;
    w1.x = acc[i][4] + bvv; w1.y = acc[i][5] + bvv; w1.z = acc[i][6] + bvv; w1.w = acc[i][7] + bvv;
    float* dst = gxT + base + (size_t)col * B_ + tx * 8;
    *(float4*)(dst)     = w0;
    *(float4*)(dst + 4) = w1;
  }
}

// ---------------------------------------------------------------------------
// One-time weight pre-transpose: wp[dir][ph][slc][g*4+c][k] (24 KB/slice)
// (unchanged — validated round 9)
// ---------------------------------------------------------------------------
__global__ __launch_bounds__(256) void wprep_kernel(
    const float* __restrict__ Uhf, const float* __restrict__ Uhb,
    const float* __restrict__ tUf, const float* __restrict__ tUb,
    float* __restrict__ wp)
{
  const int slc = blockIdx.x;        // 0..127
  const int ph  = blockIdx.y;        // 0..2
  const int dir = blockIdx.z;        // 0..1
  const int J0  = slc * 4;
  const int t   = threadIdx.x;
  const float* U = (ph == 0) ? (dir ? Uhb : Uhf)
                             : ((dir ? tUb : tUf) + (size_t)(ph - 1) * H_ * G_);
  float* dst = wp + (size_t)((dir * 3 + ph) * 128 + slc) * 6144;
  for (int i = t; i < 1536; i += 256) {
    const int g = i >> 9;            // 0..2
    const int k = i & 511;
    const float4 v = *(const float4*)&U[(size_t)k * G_ + g * 512 + J0];
    dst[(g * 4 + 0) * 512 + k] = v.x;
    dst[(g * 4 + 1) * 512 + k] = v.y;
    dst[(g * 4 + 2) * 512 + k] = v.z;
    dst[(g * 4 + 3) * 512 + k] = v.w;
  }
}

// ---------------------------------------------------------------------------
// Recurrence v15 = R14 (512 thr / 8 waves; single-stage 8-set reduce) with
// the ENTIRE post-barrier tail (gate-input prologue loads, 8-set reduce,
// gate math) guarded by w < 4 — waves 4..7 previously duplicated all of it
// and discarded the result. Wave-uniform branch; barriers stay uniform.
// 768 launches; 256 WGs; wg -> (dir = wg&1, slc = wg>>1).
// Buffers: ph0: hs->h1, ph1: h1->h2, ph2: h2->hs.
// ---------------------------------------------------------------------------

#define LOADC(BUF, C)                                                          \
  do {                                                                         \
    _Pragma("unroll") for (int it = 0; it < 16; ++it)                          \
        BUF[it] = s4k[((C) * 16 + it) * 32];                                   \
  } while (0)

#define COMPUTE(BUF, C)                                                        \
  do {                                                                         \
    _Pragma("unroll") for (int k4 = 0; k4 < 4; ++k4) {                         \
      const int ko = kbase + (C) * 16 + k4 * 4;                                \
      const float4 hv0 = BUF[k4 * 4 + 0];                                      \
      const float4 hv1 = BUF[k4 * 4 + 1];                                      \
      const float4 hv2 = BUF[k4 * 4 + 2];                                      \
      const float4 hv3 = BUF[k4 * 4 + 3];                                      \
      _Pragma("unroll") for (int g = 0; g < 3; ++g) {                          \
        _Pragma("unroll") for (int c = 0; c < 2; ++c) {                        \
          const float4 wv =                                                    \
              *(const float4*)&WL[(size_t)(g * 4 + 2 * cg + c) * 512 + ko];    \
          acc[g][c][0] = fmaf(hv0.x, wv.x, fmaf(hv1.x, wv.y,                   \
                          fmaf(hv2.x, wv.z, fmaf(hv3.x, wv.w, acc[g][c][0])))); \
          acc[g][c][1] = fmaf(hv0.y, wv.x, fmaf(hv1.y, wv.y,                   \
                          fmaf(hv2.y, wv.z, fmaf(hv3.y, wv.w, acc[g][c][1])))); \
          acc[g][c][2] = fmaf(hv0.z, wv.x, fmaf(hv1.z, wv.y,                   \
                          fmaf(hv2.z, wv.z, fmaf(hv3.z, wv.w, acc[g][c][2])))); \
          acc[g][c][3] = fmaf(hv0.w, wv.x, fmaf(hv1.w, wv.y,                   \
                          fmaf(hv2.w, wv.z, fmaf(hv3.w, wv.w, acc[g][c][3])))); \
        }                                                                      \
      }                                                                        \
    }                                                                          \
  } while (0)

template <bool USE_WP>
__global__ __launch_bounds__(512) void rec_phase(
    const float* __restrict__ gxT, const float* __restrict__ maskp,
    const float* __restrict__ Uhf, const float* __restrict__ Uhb,
    const float* __restrict__ tUf, const float* __restrict__ tUb,
    const float* __restrict__ tbf, const float* __restrict__ tbb,
    const float* hin, float* hout, const float* hsp,
    const float* __restrict__ wp,
    float* __restrict__ outp, int step, int ph)
{
  extern __shared__ float sm[];
  float* WL   = sm;                      // [12][512]   = 24 KB
  float* SW   = sm + 12 * 512;           // [8][12][128] = 48 KB
  float* OUTS = SW + 8 * 12 * 128;       // [4][128]    = 2 KB

  const int wg   = blockIdx.x;
  const int dir  = wg & 1;
  const int slc  = wg >> 1;       // 0..127
  const int J0   = slc * 4;
  const int t    = threadIdx.x;
  const int lane = t & 63;
  const int w    = t >> 6;        // 0..7
  const int kbase = w * 64;       // 8-way k-split
  const int bq   = lane & 31;     // batch quad index (GEMM tile)
  const int cg   = lane >> 5;     // h-col pair within the 4-col slice
  const int b0   = lane * 2;      // combine-path batch pair
  const int c2   = w & 3;         // combine col (valid for w<4)
  const int j    = J0 + c2;
  const int l    = dir ? (L_ - 1 - step) : step;

  const float* hinf = hin + (size_t)dir * 65536;           // [512][128]
  float2*       hout2 = ((float2*)hout)     + (size_t)dir * 32768;
  const float2* hin2 = ((const float2*)hin) + (size_t)dir * 32768;
  const float2* hs2  = ((const float2*)hsp) + (size_t)dir * 32768;
  const float4* s4k = ((const float4*)hinf) + bq + (size_t)kbase * 32;

  // ---- h prologue loads first (latency hides under staging)
  float4 A0[16], A1[16];
  LOADC(A0, 0);
  LOADC(A1, 1);

  // gate-input prologue — only the waves that will consume it (w < 4)
  float2 xz, xr, xn, mv, hc, hp;
  xz.x = xz.y = xr.x = xr.y = xn.x = xn.y = 0.f;
  mv.x = mv.y = 0.f; hc.x = hc.y = 0.f; hp.x = hp.y = 0.f;
  if (w < 4) {
    if (ph == 0) {
      const size_t gb = (((size_t)dir * L_ + l) * G_) * B_;
      xz = *(const float2*)&gxT[gb + (size_t)j * B_ + b0];
      xr = *(const float2*)&gxT[gb + (size_t)(512 + j) * B_ + b0];
      xn = *(const float2*)&gxT[gb + (size_t)(1024 + j) * B_ + b0];
      hp = hin2[(size_t)j * 64 + lane];
    } else if (ph == 1) {
      hc = hin2[(size_t)j * 64 + lane];
    } else {
      hc = hin2[(size_t)j * 64 + lane];
      hp = hs2[(size_t)j * 64 + lane];
      mv = *(const float2*)&maskp[l * B_ + b0];
    }
  }

  // ---- stage this phase's 24 KB weight slice into LDS (512 threads)
  if constexpr (USE_WP) {
    const float* slice = wp + (size_t)((dir * 3 + ph) * 128 + slc) * 6144;
    for (int i = t * 4; i < 6144; i += 2048)
      *(float4*)&WL[i] = *(const float4*)&slice[i];
  } else {
    const float* U = (ph == 0) ? (dir ? Uhb : Uhf)
                               : ((dir ? tUb : tUf) + (size_t)(ph - 1) * H_ * G_);
    for (int i = t; i < 1536; i += 512) {
      const int g = i >> 9;
      const int k = i & 511;
      const float4 v = *(const float4*)&U[(size_t)k * G_ + g * 512 + J0];
      WL[(g * 4 + 0) * 512 + k] = v.x;
      WL[(g * 4 + 1) * 512 + k] = v.y;
      WL[(g * 4 + 2) * 512 + k] = v.z;
      WL[(g * 4 + 3) * 512 + k] = v.w;
    }
  }
  __syncthreads();

  float acc[3][2][4];
#pragma unroll
  for (int g = 0; g < 3; ++g)
#pragma unroll
    for (int c = 0; c < 2; ++c)
#pragma unroll
      for (int b = 0; b < 4; ++b) acc[g][c][b] = 0.f;

  // 4 chunks of 16 k-rows, 1-deep register double-buffer
  COMPUTE(A0, 0); LOADC(A0, 2);
  COMPUTE(A1, 1); LOADC(A1, 3);
  COMPUTE(A0, 2);
  COMPUTE(A1, 3);

  // ---- single-stage: every wave writes its own SW set
#pragma unroll
  for (int g = 0; g < 3; ++g)
#pragma unroll
    for (int c = 0; c < 2; ++c) {
      float4 p;
      p.x = acc[g][c][0]; p.y = acc[g][c][1];
      p.z = acc[g][c][2]; p.w = acc[g][c][3];
      *(float4*)&SW[(size_t)(w * 12 + g * 4 + 2 * cg + c) * 128 + bq * 4] = p;
    }
  __syncthreads();

  // ---- tail: reduce + gates only on the consuming waves (w < 4)
  if (w < 4) {
    float az0 = 0.f, az1 = 0.f, ar0 = 0.f, ar1 = 0.f, an0 = 0.f, an1 = 0.f;
#pragma unroll
    for (int w8 = 0; w8 < 8; ++w8) {
      const float2 pz = *(const float2*)&SW[(size_t)(w8 * 12 + 0 + c2) * 128 + b0];
      const float2 pr = *(const float2*)&SW[(size_t)(w8 * 12 + 4 + c2) * 128 + b0];
      const float2 pn = *(const float2*)&SW[(size_t)(w8 * 12 + 8 + c2) * 128 + b0];
      az0 += pz.x; az1 += pz.y; ar0 += pr.x; ar1 += pr.y; an0 += pn.x; an1 += pn.y;
    }

    if (ph == 0) {
      float2 st;
      {
        const float z = sigm(xz.x + az0);
        const float r = sigm(xr.x + ar0);
        const float n = tanhf(xn.x + r * an0);
        st.x = (1.0f - z) * hp.x + z * n;
      }
      {
        const float z = sigm(xz.y + az1);
        const float r = sigm(xr.y + ar1);
        const float n = tanhf(xn.y + r * an1);
        st.y = (1.0f - z) * hp.y + z * n;
      }
      hout2[(size_t)j * 64 + lane] = st;
    } else if (ph == 1) {
      const float* tb = dir ? tbb : tbf;
      const float bz = tb[j], br = tb[512 + j], bn = tb[1024 + j];
      float2 st;
      {
        const float z = sigm(az0 + bz);
        const float r = sigm(ar0 + br);
        const float n = tanhf(r * (an0 + bn));
        st.x = (1.0f - z) * hc.x + z * n;
      }
      {
        const float z = sigm(az1 + bz);
        const float r = sigm(ar1 + br);
        const float n = tanhf(r * (an1 + bn));
        st.y = (1.0f - z) * hc.y + z * n;
      }
      hout2[(size_t)j * 64 + lane] = st;
    } else {
      const float* tb = dir ? tbb : tbf;
      const float bz = tb[G_ + j], br = tb[G_ + 512 + j], bn = tb[G_ + 1024 + j];
      float hin0, hin1;
      {
        const float z = sigm(az0 + bz);
        const float r = sigm(ar0 + br);
        const float n = tanhf(r * (an0 + bn));
        hin0 = (1.0f - z) * hc.x + z * n;
      }
      {
        const float z = sigm(az1 + bz);
        const float r = sigm(ar1 + br);
        const float n = tanhf(r * (an1 + bn));
        hin1 = (1.0f - z) * hc.y + z * n;
      }
      const float hn0 = mv.x * hin0 + (1.0f - mv.x) * hp.x;
      const float hn1 = mv.y * hin1 + (1.0f - mv.y) * hp.y;
      float2 st; st.x = hn0; st.y = hn1;
      hout2[(size_t)j * 64 + lane] = st;             // hout == hstate
      OUTS[c2 * 128 + b0]     = hn0 * mv.x;
      OUTS[c2 * 128 + b0 + 1] = hn1 * mv.y;
    }
  }

  if (ph == 2) {
    __syncthreads();
    if (t < B_) {
      float4 o;
      o.x = OUTS[0 * 128 + t];
      o.y = OUTS[1 * 128 + t];
      o.z = OUTS[2 * 128 + t];
      o.w = OUTS[3 * 128 + t];
      *(float4*)(&outp[((size_t)l * B_ + t) * 1024 + dir * 512 + J0]) = o;
    }
  }
}

// ---------------------------------------------------------------------------
extern "C" void kernel_launch(void* const* d_in, const int* in_sizes, int n_in,
                              void* d_out, int out_size, void* d_ws, size_t ws_size,
                              hipStream_t stream) {
  const int*   xs   = (const int*)d_in[0];
  const float* mask = (const float*)d_in[1];
  const float* emb  = (const float*)d_in[2];
  const float* fWx  = (const float*)d_in[3];
  const float* fUh  = (const float*)d_in[4];
  const float* fb   = (const float*)d_in[5];
  const float* bWx  = (const float*)d_in[6];
  const float* bUh  = (const float*)d_in[7];
  const float* bb   = (const float*)d_in[8];
  const float* ftU  = (const float*)d_in[9];
  const float* ftb  = (const float*)d_in[10];
  const float* btU  = (const float*)d_in[11];
  const float* btb  = (const float*)d_in[12];
  float* out = (float*)d_out;

  // ws: gxT[2][256][1536][128] | hstate | htmp1 | htmp2 | (optional) wp
  float* gxT    = (float*)d_ws;
  float* hstate = gxT + (size_t)2 * L_ * G_ * B_;
  float* htmp1  = hstate + (size_t)2 * H_ * B_;
  float* htmp2  = htmp1 + (size_t)2 * H_ * B_;
  float* wp_buf = htmp2 + (size_t)2 * H_ * B_;

  const size_t need_wp = ((size_t)2 * L_ * G_ * B_ + (size_t)6 * H_ * B_ +
                          (size_t)2 * 3 * 128 * 6144) * sizeof(float);
  const bool use_wp = (ws_size >= need_wp);
  const float* wpp = use_wp ? wp_buf : nullptr;

  const unsigned lds_bytes =
      (12 * 512 + 8 * 12 * 128 + 4 * 128) * sizeof(float);   // 75776 B

  // zero initial h (replay-safe)
  hipMemsetAsync(hstate, 0, (size_t)2 * H_ * B_ * sizeof(float), stream);

  if (use_wp) {
    dim3 gW(128, 3, 2);
    wprep_kernel<<<gW, 256, 0, stream>>>(fUh, bUh, ftU, btU, wp_buf);
  }

  dim3 gA(G_ / 128, L_, 2);
  gx_kernel<<<gA, 256, 0, stream>>>(xs, emb, fWx, fb, bWx, bb, gxT);

  if (use_wp) {
    for (int step = 0; step < L_; ++step) {
      rec_phase<true><<<256, 512, lds_bytes, stream>>>(
          gxT, mask, fUh, bUh, ftU, btU, ftb, btb,
          hstate, htmp1, hstate, wpp, out, step, 0);
      rec_phase<true><<<256, 512, lds_bytes, stream>>>(
          gxT, mask, fUh, bUh, ftU, btU, ftb, btb,
          htmp1, htmp2, hstate, wpp, out, step, 1);
      rec_phase<true><<<256, 512, lds_bytes, stream>>>(
          gxT, mask, fUh, bUh, ftU, btU, ftb, btb,
          htmp2, hstate, hstate, wpp, out, step, 2);
    }
  } else {
    for (int step = 0; step < L_; ++step) {
      rec_phase<false><<<256, 512, lds_bytes, stream>>>(
          gxT, mask, fUh, bUh, ftU, btU, ftb, btb,
          hstate, htmp1, hstate, wpp, out, step, 0);
      rec_phase<false><<<256, 512, lds_bytes, stream>>>(
          gxT, mask, fUh, bUh, ftU, btU, ftb, btb,
          htmp1, htmp2, hstate, wpp, out, step, 1);
      rec_phase<false><<<256, 512, lds_bytes, stream>>>(
          gxT, mask, fUh, bUh, ftU, btU, ftb, btb,
          htmp2, hstate, hstate, wpp, out, step, 2);
    }
  }
}